// Round 2
// baseline (634.390 us; speedup 1.0000x reference)
//
#include <hip/hip_runtime.h>
#include <math.h>

// FlashMultiHeadAttention: B=32 S=500 H=1024 NH=16 HD=64, rope + rel-pos-bias + key-pad mask.
// Pipeline: [mask detect/expand] -> [f32->bf16 cvt] -> [QKV proj GEMM bf16-MFMA]
//           -> [rope+transpose] -> [flash attn] -> [out proj GEMM, f32 out]

typedef unsigned short u16;
typedef unsigned int   u32;
using bf16x8 = __attribute__((ext_vector_type(8))) short;
using f32x4  = __attribute__((ext_vector_type(4))) float;
using u16x4  = __attribute__((ext_vector_type(4))) unsigned short;

#define DEV __device__ __forceinline__

DEV u16 f2bf(float f) {                 // RNE f32 -> bf16
  union { float f; u32 u; } c; c.f = f;
  u32 u = c.u;
  u32 r = u + 0x7FFFu + ((u >> 16) & 1u);
  return (u16)(r >> 16);
}
DEV float bf2f(u16 h) {
  union { u32 u; float f; } c; c.u = ((u32)h) << 16;
  return c.f;
}

// async global->LDS, 16B per lane; dest must be wave-uniform base + lane*16 (linear).
DEV void async16(void* l, const void* g) {
  __builtin_amdgcn_global_load_lds(
      (__attribute__((address_space(1))) unsigned int*)g,
      (__attribute__((address_space(3))) unsigned int*)l, 16, 0, 0);
}

// ---------------- mask prep: detect bool storage (i32 / f32 / u8), expand to f32 bias -------------
__global__ __launch_bounds__(256) void mask_prep(const void* __restrict__ mraw,
                                                 float* __restrict__ mb) {
  __shared__ int bad_i32, bad_f32;
  if (threadIdx.x == 0) { bad_i32 = 0; bad_f32 = 0; }
  __syncthreads();
  const u32* w = (const u32*)mraw;               // first 16000 bytes are safe in all layouts
  int li = 0, lf = 0;
  for (int g = threadIdx.x; g < 4000; g += 256) {
    u32 v = w[g];
    li |= !(v == 0u || v == 1u);
    lf |= !(v == 0u || v == 0x3F800000u);
  }
  if (li) atomicOr(&bad_i32, 1);
  if (lf) atomicOr(&bad_f32, 1);
  __syncthreads();
  int mode = (!bad_i32) ? 0 : ((!bad_f32) ? 1 : 2);   // 0=int32, 1=float32, 2=uint8
  for (int i = threadIdx.x; i < 16000; i += 256) {
    int v;
    if (mode == 0)      v = ((const int*)mraw)[i] != 0;
    else if (mode == 1) v = (((const float*)mraw)[i] != 0.0f);
    else                v = ((const unsigned char*)mraw)[i] != 0;
    mb[i] = v ? 0.0f : -1e30f;
  }
}

// ---------------- f32 -> bf16 convert (vectorized) ----------------
__global__ __launch_bounds__(256) void cvt_f32_bf16(const float* __restrict__ src,
                                                    u16* __restrict__ dst, int n4) {
  int i = blockIdx.x * 256 + threadIdx.x;
  int stride = gridDim.x * 256;
  for (; i < n4; i += stride) {
    f32x4 f = *(const f32x4*)(src + (size_t)i * 4);
    u16x4 o;
    o[0] = f2bf(f[0]); o[1] = f2bf(f[1]); o[2] = f2bf(f[2]); o[3] = f2bf(f[3]);
    *(u16x4*)(dst + (size_t)i * 4) = o;
  }
}

// ---------------- GEMM: C[m][n] = sum_k A[m][k]*Bw[n][k] + bias[n] ----------------
// M=16000 (grid.x=125 * BM=128), N=1024 (grid.y=8 * BN=128), K=1024, BK=32.
// 256 threads, 4 waves in 2x2; wave computes 64x64 via 4x4 frags of 16x16x32 bf16 MFMA.
template <bool OUT_BF16>
__global__ __launch_bounds__(256) void gemm_bt(const u16* __restrict__ A,
                                               const u16* __restrict__ Bw,
                                               const float* __restrict__ bias,
                                               void* __restrict__ Cout) {
  const int m0 = blockIdx.x * 128;
  const int n0 = blockIdx.y * 128;
  const int tid  = threadIdx.x;
  const int lane = tid & 63, wave = tid >> 6;
  const int wr = wave >> 1, wc = wave & 1;
  const int fr = lane & 15, fo = lane >> 4;

  __shared__ __attribute__((aligned(16))) u16 As[128 * 32];   // [row][k] 64B rows -> 2-way free
  __shared__ __attribute__((aligned(16))) u16 Bs[128 * 32];

  f32x4 acc[4][4];
#pragma unroll
  for (int mi = 0; mi < 4; ++mi)
#pragma unroll
    for (int ni = 0; ni < 4; ++ni)
#pragma unroll
      for (int j = 0; j < 4; ++j) acc[mi][ni][j] = 0.f;

  for (int kt = 0; kt < 32; ++kt) {
    __syncthreads();                 // previous iteration's reads done
#pragma unroll
    for (int i = 0; i < 2; ++i) {
      int slot = i * 256 + tid;      // 512 slots of 16B per tile
      int row = slot >> 2, seg = slot & 3;
      async16(&As[slot * 8], A + (size_t)(m0 + row) * 1024 + kt * 32 + seg * 8);
      async16(&Bs[slot * 8], Bw + (size_t)(n0 + row) * 1024 + kt * 32 + seg * 8);
    }
    __syncthreads();                 // staging complete (vmcnt drained by barrier)

    bf16x8 a[4], b[4];
#pragma unroll
    for (int mi = 0; mi < 4; ++mi)
      a[mi] = *(const bf16x8*)&As[(wr * 64 + mi * 16 + fr) * 32 + fo * 8];
#pragma unroll
    for (int ni = 0; ni < 4; ++ni)
      b[ni] = *(const bf16x8*)&Bs[(wc * 64 + ni * 16 + fr) * 32 + fo * 8];
#pragma unroll
    for (int mi = 0; mi < 4; ++mi)
#pragma unroll
      for (int ni = 0; ni < 4; ++ni)
        acc[mi][ni] = __builtin_amdgcn_mfma_f32_16x16x32_bf16(a[mi], b[ni], acc[mi][ni], 0, 0, 0);
  }

#pragma unroll
  for (int ni = 0; ni < 4; ++ni) {
    int n = n0 + wc * 64 + ni * 16 + fr;
    float bv = bias[n];
#pragma unroll
    for (int mi = 0; mi < 4; ++mi) {
#pragma unroll
      for (int r = 0; r < 4; ++r) {
        int m = m0 + wr * 64 + mi * 16 + fo * 4 + r;   // C/D: col=lane&15, row=(lane>>4)*4+reg
        float v = acc[mi][ni][r] + bv;
        if (OUT_BF16) ((u16*)Cout)[(size_t)m * 1024 + n] = f2bf(v);
        else          ((float*)Cout)[(size_t)m * 1024 + n] = v;
      }
    }
  }
}

// ---------------- rope + [B*S][H] -> [B][NH][S][HD] transpose ----------------
// ref: out[d<32] = x[d]*cos(s*invf[d]) - x[2d+1]*sin(s*invf[d])
//      out[d>=32], j=d-32: x[d]*cos(s*invf[j]) + x[2j]*sin(s*invf[j])
template <bool ROPE>
__global__ __launch_bounds__(256) void rope_tr(const u16* __restrict__ P,
                                               u16* __restrict__ R) {
  int idx = blockIdx.x * 256 + threadIdx.x;    // output element in [B][NH][S][HD]
  int d = idx & 63;
  int rest = idx >> 6;                          // bh*500 + s
  int s = rest % 500;
  int bh = rest / 500;
  int h = bh & 15;
  int b = bh >> 4;
  size_t src = (size_t)(b * 500 + s) * 1024 + h * 64;
  float x = bf2f(P[src + d]);
  float out;
  if (ROPE) {
    int j = d & 31;
    int pp = (d < 32) ? (2 * d + 1) : (2 * (d - 32));
    float xp = bf2f(P[src + pp]);
    // invf = 10000^(-j/32) = exp2(-j * log2(10000)/32)
    float ang = (float)s * exp2f(-(float)j * 0.41524100f);
    float sn, cs;
    sincosf(ang, &sn, &cs);
    out = (d < 32) ? (x * cs - xp * sn) : (x * cs + xp * sn);
  } else {
    out = x;
  }
  R[idx] = f2bf(out);
}

// ---------------- flash attention ----------------
// grid (qt=8, h=16, b=32), 256 threads / 4 waves; wave owns 16 Q rows; KV tiles of 64.
__global__ __launch_bounds__(256) void attn_kernel(const u16* __restrict__ Qr,
                                                   const u16* __restrict__ Kr,
                                                   const u16* __restrict__ Vr,
                                                   const float* __restrict__ rel_emb,
                                                   const float* __restrict__ maskbias,
                                                   u16* __restrict__ AO) {
  const int qt = blockIdx.x, h = blockIdx.y, b = blockIdx.z;
  const int bh = b * 16 + h;
  const int q0 = qt * 64;
  const int tid  = threadIdx.x;
  const int lane = tid & 63, wave = tid >> 6;
  const int fr = lane & 15, fo = lane >> 4;

  __shared__ __attribute__((aligned(16))) u16 Ks[2][64 * 32];  // [d-half][kk][32] 64B rows
  __shared__ __attribute__((aligned(16))) u16 Vt[64][72];      // [d][kk], stride 144B (16B-mult)
  __shared__ __attribute__((aligned(16))) u16 Pl[4][16][72];   // per-wave P rows
  __shared__ float rel_l[1000];                                // rel_emb column for this head

  for (int i = tid; i < 999; i += 256) rel_l[i] = rel_emb[i * 16 + h];

  // Q fragments: A-frag row = lane&15 -> q row q0+wave*16+fr (clamped; OOB rows never stored)
  const u16* Qb = Qr + ((size_t)bh * 500 + min(q0 + wave * 16 + fr, 499)) * 64;
  bf16x8 qf0 = *(const bf16x8*)(Qb + fo * 8);
  bf16x8 qf1 = *(const bf16x8*)(Qb + 32 + fo * 8);

  f32x4 o[4];
  float mrun[4], lrun[4];
#pragma unroll
  for (int nf = 0; nf < 4; ++nf)
#pragma unroll
    for (int j = 0; j < 4; ++j) o[nf][j] = 0.f;
#pragma unroll
  for (int r = 0; r < 4; ++r) { mrun[r] = -1e30f; lrun[r] = 0.f; }

  const u16* Kb = Kr + (size_t)bh * 500 * 64;
  const u16* Vb = Vr + (size_t)bh * 500 * 64;
  const float* mrow = maskbias + b * 500;

  for (int kt = 0; kt < 8; ++kt) {
    const int k0 = kt * 64;
    const int kn = min(64, 500 - k0);
    __syncthreads();                               // prev tile's LDS reads done
#pragma unroll
    for (int i = 0; i < 2; ++i) {                  // stage K, split by d-half (async)
      int slot = i * 256 + tid;                    // 0..511
      int half = slot >> 8;
      int rs = slot & 255;
      int row = rs >> 2, seg = rs & 3;
      int rowc = min(k0 + row, 499);
      async16(&Ks[half][rs * 8], Kb + (size_t)rowc * 64 + half * 32 + seg * 8);
    }
#pragma unroll
    for (int i = 0; i < 16; ++i) {                 // stage V transposed
      int flat = i * 256 + tid;
      int kk = flat >> 6, d = flat & 63;
      int kkc = min(k0 + kk, 499);
      Vt[d][kk] = Vb[(size_t)kkc * 64 + d];
    }
    __syncthreads();                               // staging complete

    // QK^T: scores 16x64 per wave
    f32x4 sacc[4];
#pragma unroll
    for (int nf = 0; nf < 4; ++nf) {
#pragma unroll
      for (int j = 0; j < 4; ++j) sacc[nf][j] = 0.f;
      bf16x8 kb0 = *(const bf16x8*)&Ks[0][(nf * 16 + fr) * 32 + fo * 8];
      bf16x8 kb1 = *(const bf16x8*)&Ks[1][(nf * 16 + fr) * 32 + fo * 8];
      sacc[nf] = __builtin_amdgcn_mfma_f32_16x16x32_bf16(qf0, kb0, sacc[nf], 0, 0, 0);
      sacc[nf] = __builtin_amdgcn_mfma_f32_16x16x32_bf16(qf1, kb1, sacc[nf], 0, 0, 0);
    }

    // scores: scale + rel bias + mask
    float p[4][4], pmax[4];
#pragma unroll
    for (int r = 0; r < 4; ++r) pmax[r] = -1e30f;
#pragma unroll
    for (int nf = 0; nf < 4; ++nf) {
      int kk = nf * 16 + fr;                       // C col = lane&15
      float mb = (kk < kn) ? mrow[k0 + kk] : -1e30f;
#pragma unroll
      for (int r = 0; r < 4; ++r) {
        int qr_ = q0 + wave * 16 + fo * 4 + r;     // C row = (lane>>4)*4+reg
        int ridx = qr_ - (k0 + kk) + 499;
        ridx = min(max(ridx, 0), 998);
        float sc = 0.125f * sacc[nf][r] + rel_l[ridx] + mb;
        p[nf][r] = sc;
        pmax[r] = fmaxf(pmax[r], sc);
      }
    }
#pragma unroll
    for (int r = 0; r < 4; ++r) {
#pragma unroll
      for (int off = 1; off < 16; off <<= 1)
        pmax[r] = fmaxf(pmax[r], __shfl_xor(pmax[r], off, 64));
    }
    float scl[4], lsum[4];
#pragma unroll
    for (int r = 0; r < 4; ++r) {
      float mnew = fmaxf(mrun[r], pmax[r]);
      scl[r] = expf(mrun[r] - mnew);
      mrun[r] = mnew;
      lsum[r] = 0.f;
    }
#pragma unroll
    for (int nf = 0; nf < 4; ++nf)
#pragma unroll
      for (int r = 0; r < 4; ++r) {
        float e = expf(p[nf][r] - mrun[r]);
        lsum[r] += e;
        Pl[wave][fo * 4 + r][nf * 16 + fr] = f2bf(e);
      }
#pragma unroll
    for (int r = 0; r < 4; ++r) {
#pragma unroll
      for (int off = 1; off < 16; off <<= 1)
        lsum[r] += __shfl_xor(lsum[r], off, 64);
      lrun[r] = lrun[r] * scl[r] + lsum[r];
    }
#pragma unroll
    for (int nf = 0; nf < 4; ++nf)
#pragma unroll
      for (int r = 0; r < 4; ++r) o[nf][r] *= scl[r];

    // PV: O += P(16x64) @ V(64x64)
    bf16x8 pa0 = *(const bf16x8*)&Pl[wave][fr][fo * 8];
    bf16x8 pa1 = *(const bf16x8*)&Pl[wave][fr][32 + fo * 8];
#pragma unroll
    for (int nf = 0; nf < 4; ++nf) {
      bf16x8 vb0 = *(const bf16x8*)&Vt[nf * 16 + fr][fo * 8];
      bf16x8 vb1 = *(const bf16x8*)&Vt[nf * 16 + fr][32 + fo * 8];
      o[nf] = __builtin_amdgcn_mfma_f32_16x16x32_bf16(pa0, vb0, o[nf], 0, 0, 0);
      o[nf] = __builtin_amdgcn_mfma_f32_16x16x32_bf16(pa1, vb1, o[nf], 0, 0, 0);
    }
  }

  // epilogue: normalize, clip, store [B*S][H] bf16
#pragma unroll
  for (int r = 0; r < 4; ++r) {
    int qr_ = q0 + wave * 16 + fo * 4 + r;
    if (qr_ >= 500) continue;
    float inv = 1.f / ((lrun[r] > 0.f) ? lrun[r] : 1.f);
#pragma unroll
    for (int nf = 0; nf < 4; ++nf) {
      float v = o[nf][r] * inv;
      v = fminf(fmaxf(v, -30.f), 30.f);
      AO[(size_t)(b * 500 + qr_) * 1024 + h * 64 + nf * 16 + fr] = f2bf(v);
    }
  }
}

// ---------------- launch ----------------
extern "C" void kernel_launch(void* const* d_in, const int* in_sizes, int n_in,
                              void* d_out, int out_size, void* d_ws, size_t ws_size,
                              hipStream_t stream) {
  const float* query = (const float*)d_in[0];
  const float* key_  = (const float*)d_in[1];
  const float* value = (const float*)d_in[2];
  const void*  mask  = d_in[3];
  const float* Wq = (const float*)d_in[4];
  const float* bq = (const float*)d_in[5];
  const float* Wk = (const float*)d_in[6];
  const float* bk = (const float*)d_in[7];
  const float* Wv = (const float*)d_in[8];
  const float* bv = (const float*)d_in[9];
  const float* Wo = (const float*)d_in[10];
  const float* bo = (const float*)d_in[11];
  const float* rel = (const float*)d_in[12];

  // ws map (bytes): [0, 8.0MB) Wb bf16 x4 | [8.0, 106.3MB) X/QKV-rope'd bf16 x3
  //                 | [106.3, 204.6MB) proj-out / attn-out bf16 x3 | [204.6MB +64KB) maskbias
  char* ws = (char*)d_ws;
  u16* Wb = (u16*)(ws);                               // 4 x 1048576 elems
  u16* Xb = (u16*)(ws + 8388608);                     // 3 x 16384000 elems (reused as Qr/Kr/Vr)
  u16* Pb = (u16*)(ws + 8388608 + 98304000);          // 3 x 16384000 elems (Qp/Kp/Vp, then AO)
  float* maskbias = (float*)(ws + 8388608 + 98304000 + 98304000);

  mask_prep<<<1, 256, 0, stream>>>(mask, maskbias);

  cvt_f32_bf16<<<512, 256, 0, stream>>>(Wq, Wb + 0 * 1048576, 262144);
  cvt_f32_bf16<<<512, 256, 0, stream>>>(Wk, Wb + 1 * 1048576, 262144);
  cvt_f32_bf16<<<512, 256, 0, stream>>>(Wv, Wb + 2 * 1048576, 262144);
  cvt_f32_bf16<<<512, 256, 0, stream>>>(Wo, Wb + 3 * 1048576, 262144);
  cvt_f32_bf16<<<2048, 256, 0, stream>>>(query, Xb + (size_t)0 * 16384000, 4096000);
  cvt_f32_bf16<<<2048, 256, 0, stream>>>(key_,  Xb + (size_t)1 * 16384000, 4096000);
  cvt_f32_bf16<<<2048, 256, 0, stream>>>(value, Xb + (size_t)2 * 16384000, 4096000);

  dim3 gg(125, 8);
  gemm_bt<true><<<gg, 256, 0, stream>>>(Xb + (size_t)0 * 16384000, Wb + 0 * 1048576, bq, Pb + (size_t)0 * 16384000);
  gemm_bt<true><<<gg, 256, 0, stream>>>(Xb + (size_t)1 * 16384000, Wb + 1 * 1048576, bk, Pb + (size_t)1 * 16384000);
  gemm_bt<true><<<gg, 256, 0, stream>>>(Xb + (size_t)2 * 16384000, Wb + 2 * 1048576, bv, Pb + (size_t)2 * 16384000);

  rope_tr<true><<<64000, 256, 0, stream>>>(Pb + (size_t)0 * 16384000, Xb + (size_t)0 * 16384000);
  rope_tr<true><<<64000, 256, 0, stream>>>(Pb + (size_t)1 * 16384000, Xb + (size_t)1 * 16384000);
  rope_tr<false><<<64000, 256, 0, stream>>>(Pb + (size_t)2 * 16384000, Xb + (size_t)2 * 16384000);

  attn_kernel<<<dim3(8, 16, 32), 256, 0, stream>>>(
      Xb + (size_t)0 * 16384000, Xb + (size_t)1 * 16384000, Xb + (size_t)2 * 16384000,
      rel, maskbias, Pb);

  gemm_bt<false><<<gg, 256, 0, stream>>>(Pb, Wb + 3 * 1048576, bo, (float*)d_out);
}

// Round 3
// 483.865 us; speedup vs baseline: 1.3111x; 1.3111x over previous
//
#include <hip/hip_runtime.h>
#include <math.h>

// FlashMultiHeadAttention: B=32 S=500 H=1024 NH=16 HD=64, rope + rel-pos-bias + key-pad mask.
// Pipeline: [mask prep] [rope table] [f32->bf16 cvt] [QKV proj GEMM (XCD-swz)]
//           [rope (table) Q,K] [V transpose+swizzle] [flash attn (XCD-swz, exp2 softmax)]
//           [out proj GEMM -> f32]

typedef unsigned short u16;
typedef unsigned int   u32;
using bf16x8 = __attribute__((ext_vector_type(8))) short;
using f32x4  = __attribute__((ext_vector_type(4))) float;
using f32x2  = __attribute__((ext_vector_type(2))) float;
using u16x4  = __attribute__((ext_vector_type(4))) unsigned short;

#define DEV __device__ __forceinline__

#if __has_builtin(__builtin_amdgcn_exp2f)
#define EXP2(x) __builtin_amdgcn_exp2f(x)
#else
#define EXP2(x) exp2f(x)
#endif

DEV u16 f2bf(float f) {                 // RNE f32 -> bf16
  union { float f; u32 u; } c; c.f = f;
  u32 u = c.u;
  u32 r = u + 0x7FFFu + ((u >> 16) & 1u);
  return (u16)(r >> 16);
}
DEV float bf2f(u16 h) {
  union { u32 u; float f; } c; c.u = ((u32)h) << 16;
  return c.f;
}

// async global->LDS, 16B per lane; dest must be wave-uniform base + lane*16 (linear).
DEV void async16(void* l, const void* g) {
  __builtin_amdgcn_global_load_lds(
      (__attribute__((address_space(1))) unsigned int*)g,
      (__attribute__((address_space(3))) unsigned int*)l, 16, 0, 0);
}

// ---------------- mask prep: detect bool storage (i32 / f32 / u8), expand to f32 bias ----------
__global__ __launch_bounds__(256) void mask_prep(const void* __restrict__ mraw,
                                                 float* __restrict__ mb) {
  __shared__ int bad_i32, bad_f32;
  if (threadIdx.x == 0) { bad_i32 = 0; bad_f32 = 0; }
  __syncthreads();
  const u32* w = (const u32*)mraw;
  int li = 0, lf = 0;
  for (int g = threadIdx.x; g < 4000; g += 256) {
    u32 v = w[g];
    li |= !(v == 0u || v == 1u);
    lf |= !(v == 0u || v == 0x3F800000u);
  }
  if (li) atomicOr(&bad_i32, 1);
  if (lf) atomicOr(&bad_f32, 1);
  __syncthreads();
  int mode = (!bad_i32) ? 0 : ((!bad_f32) ? 1 : 2);   // 0=int32, 1=float32, 2=uint8
  for (int i = threadIdx.x; i < 16000; i += 256) {
    int v;
    if (mode == 0)      v = ((const int*)mraw)[i] != 0;
    else if (mode == 1) v = (((const float*)mraw)[i] != 0.0f);
    else                v = ((const unsigned char*)mraw)[i] != 0;
    mb[i] = v ? 0.0f : -1e30f;
  }
}

// ---------------- rope cos/sin table: tab[(s*32+j)*2] = cos, +1 = sin ----------------
__global__ __launch_bounds__(256) void rope_table(float* __restrict__ tab) {
  int idx = blockIdx.x * 256 + threadIdx.x;
  if (idx >= 16000) return;
  int s = idx >> 5, j = idx & 31;
  // inv_freq = 10000^(-j/32) = exp2(-j * log2(10000)/32)
  float ang = (float)s * exp2f(-(float)j * 0.41524100f);
  float sn, cs;
  sincosf(ang, &sn, &cs);
  tab[idx * 2] = cs;
  tab[idx * 2 + 1] = sn;
}

// ---------------- f32 -> bf16 convert (vectorized) ----------------
__global__ __launch_bounds__(256) void cvt_f32_bf16(const float* __restrict__ src,
                                                    u16* __restrict__ dst, int n4) {
  int i = blockIdx.x * 256 + threadIdx.x;
  int stride = gridDim.x * 256;
  for (; i < n4; i += stride) {
    f32x4 f = *(const f32x4*)(src + (size_t)i * 4);
    u16x4 o;
    o[0] = f2bf(f[0]); o[1] = f2bf(f[1]); o[2] = f2bf(f[2]); o[3] = f2bf(f[3]);
    *(u16x4*)(dst + (size_t)i * 4) = o;
  }
}

// ---------------- GEMM: C[m][n] = sum_k A[m][k]*Bw[n][k] + bias[n] ----------------
// 1D grid 1000 = 125 m-blocks x 8 n-blocks, XCD-chunk swizzled so the 8 n-blocks
// sharing an A-panel run on the same XCD (A fetched once per XCD from HBM).
template <bool OUT_BF16>
__global__ __launch_bounds__(256) void gemm_bt(const u16* __restrict__ A,
                                               const u16* __restrict__ Bw,
                                               const float* __restrict__ bias,
                                               void* __restrict__ Cout) {
  const int bid = blockIdx.x;
  const int swz = (bid & 7) * 125 + (bid >> 3);   // bijective: 1000 = 8*125
  const int m0 = (swz >> 3) * 128;
  const int n0 = (swz & 7) * 128;
  const int tid  = threadIdx.x;
  const int lane = tid & 63, wave = tid >> 6;
  const int wr = wave >> 1, wc = wave & 1;
  const int fr = lane & 15, fo = lane >> 4;

  __shared__ __attribute__((aligned(16))) u16 As[128 * 32];   // 64B rows (conflict-free b128)
  __shared__ __attribute__((aligned(16))) u16 Bs[128 * 32];

  f32x4 acc[4][4];
#pragma unroll
  for (int mi = 0; mi < 4; ++mi)
#pragma unroll
    for (int ni = 0; ni < 4; ++ni)
#pragma unroll
      for (int j = 0; j < 4; ++j) acc[mi][ni][j] = 0.f;

  for (int kt = 0; kt < 32; ++kt) {
    __syncthreads();
#pragma unroll
    for (int i = 0; i < 2; ++i) {
      int slot = i * 256 + tid;
      int row = slot >> 2, seg = slot & 3;
      async16(&As[slot * 8], A + (size_t)(m0 + row) * 1024 + kt * 32 + seg * 8);
      async16(&Bs[slot * 8], Bw + (size_t)(n0 + row) * 1024 + kt * 32 + seg * 8);
    }
    __syncthreads();

    bf16x8 a[4], b[4];
#pragma unroll
    for (int mi = 0; mi < 4; ++mi)
      a[mi] = *(const bf16x8*)&As[(wr * 64 + mi * 16 + fr) * 32 + fo * 8];
#pragma unroll
    for (int ni = 0; ni < 4; ++ni)
      b[ni] = *(const bf16x8*)&Bs[(wc * 64 + ni * 16 + fr) * 32 + fo * 8];
#pragma unroll
    for (int mi = 0; mi < 4; ++mi)
#pragma unroll
      for (int ni = 0; ni < 4; ++ni)
        acc[mi][ni] = __builtin_amdgcn_mfma_f32_16x16x32_bf16(a[mi], b[ni], acc[mi][ni], 0, 0, 0);
  }

#pragma unroll
  for (int ni = 0; ni < 4; ++ni) {
    int n = n0 + wc * 64 + ni * 16 + fr;
    float bv = bias[n];
#pragma unroll
    for (int mi = 0; mi < 4; ++mi) {
#pragma unroll
      for (int r = 0; r < 4; ++r) {
        int m = m0 + wr * 64 + mi * 16 + fo * 4 + r;   // C/D: col=lane&15, row=(lane>>4)*4+reg
        float v = acc[mi][ni][r] + bv;
        if (OUT_BF16) ((u16*)Cout)[(size_t)m * 1024 + n] = f2bf(v);
        else          ((float*)Cout)[(size_t)m * 1024 + n] = v;
      }
    }
  }
}

// ---------------- rope (table) + [B*S][H] -> [B][NH][S][HD]; 2 outputs/thread ----------------
__global__ __launch_bounds__(256) void rope_tr2(const u16* __restrict__ P,
                                                const float* __restrict__ tab,
                                                u16* __restrict__ R) {
  int idx = blockIdx.x * 256 + threadIdx.x;   // 8,192,000 = 512 bh * 500 s * 32 j
  int j = idx & 31;
  int t = idx >> 5;                           // bh*500 + s
  int s = t % 500;
  int bh = t / 500;
  int h = bh & 15, b = bh >> 4;
  size_t src = (size_t)(b * 500 + s) * 1024 + h * 64;
  float x0 = bf2f(P[src + j]);
  float x1 = bf2f(P[src + 32 + j]);
  float xe = bf2f(P[src + 2 * j]);
  float xo = bf2f(P[src + 2 * j + 1]);
  f32x2 cn = *(const f32x2*)(tab + (s * 32 + j) * 2);
  size_t dst = (size_t)t * 64;
  R[dst + j]      = f2bf(x0 * cn[0] - xo * cn[1]);   // d<32
  R[dst + 32 + j] = f2bf(x1 * cn[0] + xe * cn[1]);   // d>=32
}

// ---------------- V transpose: [b*500+s][h*64+d] -> Vtg[bh][tile][8KB pre-swizzled] -------------
// Tile layout (u16 idx within 4096): o such that element (d = o>>6, c = (o&63) ^ ((d&7)<<3))
// holds V^T[d][c] = V[kt*64+c][d]. Reader XORs the same way -> conflict-free ds_read_b128.
__global__ __launch_bounds__(256) void transpose_v(const u16* __restrict__ Vp,
                                                   u16* __restrict__ Vtg) {
  const int kt = blockIdx.x & 7;
  const int bh = blockIdx.x >> 3;
  const int h = bh & 15, b = bh >> 4;
  const int tid = threadIdx.x;
  __shared__ __attribute__((aligned(16))) u16 Vl[64 * 64];   // [s][d]
#pragma unroll
  for (int i = 0; i < 2; ++i) {
    int chunk = i * 256 + tid;                 // 512 chunks of 8 u16
    int srow = chunk >> 3, seg = chunk & 7;
    int s = kt * 64 + srow;
    bf16x8 v;
#pragma unroll
    for (int p = 0; p < 8; ++p) v[p] = 0;
    if (s < 500)
      v = *(const bf16x8*)(Vp + (size_t)(b * 500 + s) * 1024 + h * 64 + seg * 8);
    *(bf16x8*)&Vl[srow * 64 + seg * 8] = v;
  }
  __syncthreads();
  u16* out = Vtg + ((size_t)bh * 8 + kt) * 4096;
#pragma unroll
  for (int i = 0; i < 2; ++i) {
    int chunk = i * 256 + tid;
    int d = chunk >> 3;
    int c0 = ((chunk & 7) * 8) ^ ((d & 7) << 3);
    bf16x8 v;
#pragma unroll
    for (int p = 0; p < 8; ++p) v[p] = (short)Vl[(c0 + p) * 64 + d];
    *(bf16x8*)(out + chunk * 8) = v;
  }
}

// ---------------- flash attention ----------------
// 1D grid 4096, XCD-swizzled so the 8 q-tiles of one head stay on one XCD (K/V L2 reuse).
// 4 waves; wave owns 16 Q rows; KV tiles of 64; exp2-domain online softmax.
__global__ __launch_bounds__(256) void attn_kernel(const u16* __restrict__ Qr,
                                                   const u16* __restrict__ Kr,
                                                   const u16* __restrict__ Vtg,
                                                   const float* __restrict__ rel_emb,
                                                   const float* __restrict__ maskbias,
                                                   u16* __restrict__ AO) {
  const int bid = blockIdx.x;
  const int swz = (bid & 7) * 512 + (bid >> 3);   // bijective: 4096 = 8*512
  const int qt = swz & 7;
  const int bh = swz >> 3;
  const int h = bh & 15, b = bh >> 4;
  const int q0 = qt * 64;
  const int tid = threadIdx.x;
  const int lane = tid & 63, wave = tid >> 6;
  const int fr = lane & 15, fo = lane >> 4;

  __shared__ __attribute__((aligned(16))) u16 Ks[2][64 * 32];  // [d-half][kk][32], 64B rows
  __shared__ __attribute__((aligned(16))) u16 Vt[4096];        // pre-swizzled V^T tile
  __shared__ __attribute__((aligned(16))) u16 Pl[4][1024];     // per-wave P, XOR-swizzled 128B rows
  __shared__ float rel2[576];                                  // rel window * log2e
  __shared__ float mrow_l[512];                                // mask bias row (pad = -1e30)

  const float LOG2E = 1.44269504f;
  for (int i = tid; i < 576; i += 256) {
    int g = min(q0 + i, 998);
    rel2[i] = rel_emb[g * 16 + h] * LOG2E;
  }
  for (int i = tid; i < 512; i += 256)
    mrow_l[i] = (i < 500) ? maskbias[b * 500 + i] : -1e30f;
  // first __syncthreads in the tile loop covers these stores

  const u16* Qb = Qr + ((size_t)bh * 500 + min(q0 + wave * 16 + fr, 499)) * 64;
  bf16x8 qf0 = *(const bf16x8*)(Qb + fo * 8);
  bf16x8 qf1 = *(const bf16x8*)(Qb + 32 + fo * 8);

  f32x4 o[4];
  float mrun[4], lrun[4];
#pragma unroll
  for (int nf = 0; nf < 4; ++nf)
#pragma unroll
    for (int j = 0; j < 4; ++j) o[nf][j] = 0.f;
#pragma unroll
  for (int r = 0; r < 4; ++r) { mrun[r] = -1e30f; lrun[r] = 0.f; }

  const u16* Kb  = Kr + (size_t)bh * 500 * 64;
  const u16* Vgb = Vtg + (size_t)bh * 32768;
  u16* Plw = &Pl[wave][0];

  const int qbase = wave * 16 + fo * 4;
  const int sw8 = (fr & 7) << 3;
  const int c0 = (fo * 8) ^ sw8;          // swizzled k-chunk (k 0..31 half)
  const int c1 = (32 + fo * 8) ^ sw8;     // swizzled k-chunk (k 32..63 half)
  const float SC = 0.18033688f;           // 0.125 * log2(e)

  for (int kt = 0; kt < 8; ++kt) {
    const int k0 = kt * 64;
    __syncthreads();                      // prev tile's LDS reads done
#pragma unroll
    for (int i = 0; i < 2; ++i) {         // stage K (d-half split)
      int slot = i * 256 + tid;
      int half = slot >> 8, rs = slot & 255;
      int rowc = min(k0 + (rs >> 2), 499);
      async16(&Ks[half][rs * 8], Kb + (size_t)rowc * 64 + half * 32 + (rs & 3) * 8);
    }
#pragma unroll
    for (int i = 0; i < 2; ++i) {         // stage V^T tile (linear copy of pre-swizzled)
      int slot = i * 256 + tid;
      async16(&Vt[slot * 8], Vgb + kt * 4096 + slot * 8);
    }
    __syncthreads();                      // staging complete

    // QK^T: scores 16x64 per wave
    f32x4 sacc[4];
    __builtin_amdgcn_s_setprio(1);
#pragma unroll
    for (int nf = 0; nf < 4; ++nf) {
#pragma unroll
      for (int j = 0; j < 4; ++j) sacc[nf][j] = 0.f;
      bf16x8 kb0 = *(const bf16x8*)&Ks[0][(nf * 16 + fr) * 32 + fo * 8];
      bf16x8 kb1 = *(const bf16x8*)&Ks[1][(nf * 16 + fr) * 32 + fo * 8];
      sacc[nf] = __builtin_amdgcn_mfma_f32_16x16x32_bf16(qf0, kb0, sacc[nf], 0, 0, 0);
      sacc[nf] = __builtin_amdgcn_mfma_f32_16x16x32_bf16(qf1, kb1, sacc[nf], 0, 0, 0);
    }
    __builtin_amdgcn_s_setprio(0);

    // scores in log2 domain: s2 = sacc*0.125*log2e + rel2 + mask
    float p2[4][4], pmax[4];
#pragma unroll
    for (int r = 0; r < 4; ++r) pmax[r] = -1e30f;
    const int cbase = qbase + 499 - k0;
#pragma unroll
    for (int nf = 0; nf < 4; ++nf) {
      int kk = nf * 16 + fr;               // C col = lane&15
      float mb = mrow_l[k0 + kk];
      int t0 = cbase - kk;
#pragma unroll
      for (int r = 0; r < 4; ++r) {        // C row = (lane>>4)*4+reg
        int rl = max(t0 + r, 0);
        float s2 = fmaf(sacc[nf][r], SC, rel2[rl] + mb);
        p2[nf][r] = s2;
        pmax[r] = fmaxf(pmax[r], s2);
      }
    }
#pragma unroll
    for (int r = 0; r < 4; ++r) {
#pragma unroll
      for (int off = 1; off < 16; off <<= 1)
        pmax[r] = fmaxf(pmax[r], __shfl_xor(pmax[r], off, 64));
    }
    float scl[4], lsum[4];
#pragma unroll
    for (int r = 0; r < 4; ++r) {
      float mnew = fmaxf(mrun[r], pmax[r]);
      scl[r] = EXP2(mrun[r] - mnew);
      mrun[r] = mnew;
      lsum[r] = 0.f;
    }
#pragma unroll
    for (int nf = 0; nf < 4; ++nf) {
      int kk = nf * 16 + fr;
#pragma unroll
      for (int r = 0; r < 4; ++r) {
        float e = EXP2(p2[nf][r] - mrun[r]);
        lsum[r] += e;
        int q = fo * 4 + r;
        Plw[q * 64 + (kk ^ ((q & 7) << 3))] = f2bf(e);
      }
    }
#pragma unroll
    for (int r = 0; r < 4; ++r) {
#pragma unroll
      for (int off = 1; off < 16; off <<= 1)
        lsum[r] += __shfl_xor(lsum[r], off, 64);
      lrun[r] = lrun[r] * scl[r] + lsum[r];
    }
#pragma unroll
    for (int nf = 0; nf < 4; ++nf)
#pragma unroll
      for (int r = 0; r < 4; ++r) o[nf][r] *= scl[r];

    // PV: O += P(16x64) @ V(64x64); swizzled conflict-free reads
    bf16x8 pa0 = *(const bf16x8*)&Plw[fr * 64 + c0];
    bf16x8 pa1 = *(const bf16x8*)&Plw[fr * 64 + c1];
    __builtin_amdgcn_s_setprio(1);
#pragma unroll
    for (int nf = 0; nf < 4; ++nf) {
      bf16x8 vb0 = *(const bf16x8*)&Vt[(nf * 16 + fr) * 64 + c0];
      bf16x8 vb1 = *(const bf16x8*)&Vt[(nf * 16 + fr) * 64 + c1];
      o[nf] = __builtin_amdgcn_mfma_f32_16x16x32_bf16(pa0, vb0, o[nf], 0, 0, 0);
      o[nf] = __builtin_amdgcn_mfma_f32_16x16x32_bf16(pa1, vb1, o[nf], 0, 0, 0);
    }
    __builtin_amdgcn_s_setprio(0);
  }

  // epilogue: normalize, clip, store [B*S][H] bf16
#pragma unroll
  for (int r = 0; r < 4; ++r) {
    int qr_ = q0 + wave * 16 + fo * 4 + r;
    if (qr_ >= 500) continue;
    float inv = 1.f / ((lrun[r] > 0.f) ? lrun[r] : 1.f);
#pragma unroll
    for (int nf = 0; nf < 4; ++nf) {
      float v = o[nf][r] * inv;
      v = fminf(fmaxf(v, -30.f), 30.f);
      AO[(size_t)(b * 500 + qr_) * 1024 + h * 64 + nf * 16 + fr] = f2bf(v);
    }
  }
}

// ---------------- launch ----------------
extern "C" void kernel_launch(void* const* d_in, const int* in_sizes, int n_in,
                              void* d_out, int out_size, void* d_ws, size_t ws_size,
                              hipStream_t stream) {
  const float* query = (const float*)d_in[0];
  const float* key_  = (const float*)d_in[1];
  const float* value = (const float*)d_in[2];
  const void*  mask  = d_in[3];
  const float* Wq = (const float*)d_in[4];
  const float* bq = (const float*)d_in[5];
  const float* Wk = (const float*)d_in[6];
  const float* bk = (const float*)d_in[7];
  const float* Wv = (const float*)d_in[8];
  const float* bv = (const float*)d_in[9];
  const float* Wo = (const float*)d_in[10];
  const float* bo = (const float*)d_in[11];
  const float* rel = (const float*)d_in[12];

  // ws map (bytes), total 172,420,608:
  //  [0, 8.39M)  Wb bf16 x4
  //  +32.768M    Xq : query-bf16, later roped Q
  //  +32.768M    Xk : key-bf16,  later roped K
  //  +32.768M    Pq : value-bf16, then Q-proj; later start of Vtg
  //  +32.768M    Pk : K-proj; Vtg spills 768KB into its head (after ropeK consumed it)
  //  +32.768M    Pv : V-proj; later AO (attn out)
  //  +64K        maskbias | +128K rope tab
  char* ws = (char*)d_ws;
  u16* Wb = (u16*)ws;
  u16* Xq = (u16*)(ws + 8388608);
  u16* Xk = (u16*)(ws + 8388608 + 1 * 32768000);
  u16* Pq = (u16*)(ws + 8388608 + 2 * 32768000);
  u16* Pk = (u16*)(ws + 8388608 + 3 * 32768000);
  u16* Pv = (u16*)(ws + 8388608 + 4 * 32768000);
  u16* Xv = Pq;                                    // value-bf16 (pre-gemmQ)
  u16* Vtg = Pq;                                   // 33,554,432 B (Pq + head of Pk)
  u16* AO  = Pv;
  float* maskbias = (float*)(ws + 8388608 + 5 * 32768000);
  float* tab      = (float*)(ws + 8388608 + 5 * 32768000 + 64000);

  mask_prep<<<1, 256, 0, stream>>>(mask, maskbias);
  rope_table<<<63, 256, 0, stream>>>(tab);

  cvt_f32_bf16<<<512, 256, 0, stream>>>(Wq, Wb + 0 * 1048576, 262144);
  cvt_f32_bf16<<<512, 256, 0, stream>>>(Wk, Wb + 1 * 1048576, 262144);
  cvt_f32_bf16<<<512, 256, 0, stream>>>(Wv, Wb + 2 * 1048576, 262144);
  cvt_f32_bf16<<<512, 256, 0, stream>>>(Wo, Wb + 3 * 1048576, 262144);
  cvt_f32_bf16<<<2048, 256, 0, stream>>>(query, Xq, 4096000);
  cvt_f32_bf16<<<2048, 256, 0, stream>>>(key_,  Xk, 4096000);
  cvt_f32_bf16<<<2048, 256, 0, stream>>>(value, Xv, 4096000);

  // V first (its A input lives where gemmQ will write)
  gemm_bt<true><<<1000, 256, 0, stream>>>(Xv, Wb + 2 * 1048576, bv, Pv);
  gemm_bt<true><<<1000, 256, 0, stream>>>(Xq, Wb + 0 * 1048576, bq, Pq);
  gemm_bt<true><<<1000, 256, 0, stream>>>(Xk, Wb + 1 * 1048576, bk, Pk);

  rope_tr2<<<32000, 256, 0, stream>>>(Pq, tab, Xq);
  rope_tr2<<<32000, 256, 0, stream>>>(Pk, tab, Xk);
  transpose_v<<<4096, 256, 0, stream>>>(Pv, Vtg);

  attn_kernel<<<4096, 256, 0, stream>>>(Xq, Xk, Vtg, rel, maskbias, AO);

  gemm_bt<false><<<1000, 256, 0, stream>>>(AO, Wb + 3 * 1048576, bo, (float*)d_out);
}

// Round 5
// 446.925 us; speedup vs baseline: 1.4195x; 1.0827x over previous
//
#include <hip/hip_runtime.h>
#include <math.h>

// FlashMultiHeadAttention: B=32 S=500 H=1024 NH=16 HD=64, rope + rel-pos-bias + key-pad mask.
// Pipeline: [mask->bytes] [gather-list scan] [rope table] [f32->bf16 cvt]
//           [QKV proj GEMM, 2-phase prefetch] [rope Q] [rope+gather+swizzle K tiles]
//           [gather+transpose+swizzle V tiles] [flash attn: masked-k compressed,
//            swapped QK^T, in-register softmax, prefetch pipeline] [out proj GEMM]

typedef unsigned short u16;
typedef unsigned int   u32;
typedef unsigned char  u8;
using bf16x8 = __attribute__((ext_vector_type(8))) short;
using f32x4  = __attribute__((ext_vector_type(4))) float;
using f32x2  = __attribute__((ext_vector_type(2))) float;
using u16x4  = __attribute__((ext_vector_type(4))) unsigned short;

#define DEV __device__ __forceinline__

#if __has_builtin(__builtin_amdgcn_exp2f)
#define EXP2(x) __builtin_amdgcn_exp2f(x)
#else
#define EXP2(x) exp2f(x)
#endif

DEV u16 f2bf(float f) {                 // RNE f32 -> bf16
  union { float f; u32 u; } c; c.f = f;
  u32 u = c.u;
  return (u16)((u + 0x7FFFu + ((u >> 16) & 1u)) >> 16);
}
DEV float bf2f(u16 h) {
  union { u32 u; float f; } c; c.u = ((u32)h) << 16;
  return c.f;
}
DEV u32 packbf(float a, float b) {      // half-up rounding, packed pair
  union { float f; u32 u; } x, y; x.f = a; y.f = b;
  return ((x.u + 0x8000u) >> 16) | ((y.u + 0x8000u) & 0xFFFF0000u);
}

// async global->LDS, 16B/lane; LDS dest = wave-uniform base + lane*16 (linear).
DEV void async16(void* l, const void* g) {
  __builtin_amdgcn_global_load_lds(
      (__attribute__((address_space(1))) unsigned int*)g,
      (__attribute__((address_space(3))) unsigned int*)l, 16, 0, 0);
}

// ---------------- mask prep: detect bool storage (i32/f32/u8), emit bytes ----------------
__global__ __launch_bounds__(256) void mask_prep(const void* __restrict__ mraw,
                                                 u8* __restrict__ maskb) {
  __shared__ int bad_i32, bad_f32;
  if (threadIdx.x == 0) { bad_i32 = 0; bad_f32 = 0; }
  __syncthreads();
  const u32* w = (const u32*)mraw;
  int li = 0, lf = 0;
  for (int g = threadIdx.x; g < 4000; g += 256) {
    u32 v = w[g];
    li |= !(v == 0u || v == 1u);
    lf |= !(v == 0u || v == 0x3F800000u);
  }
  if (li) atomicOr(&bad_i32, 1);
  if (lf) atomicOr(&bad_f32, 1);
  __syncthreads();
  int mode = (!bad_i32) ? 0 : ((!bad_f32) ? 1 : 2);   // 0=int32, 1=float32, 2=uint8
  for (int i = threadIdx.x; i < 16000; i += 256) {
    int v;
    if (mode == 0)      v = ((const int*)mraw)[i] != 0;
    else if (mode == 1) v = (((const float*)mraw)[i] != 0.0f);
    else                v = ((const u8*)mraw)[i] != 0;
    maskb[i] = (u8)v;
  }
}

// ---------------- per-batch gather list: karr[b][512] = kept token or 0xFFFF ----------------
__global__ __launch_bounds__(512) void build_gather(const u8* __restrict__ maskb,
                                                    u16* __restrict__ karr,
                                                    int* __restrict__ kept) {
  const int b = blockIdx.x;
  const int t = threadIdx.x;
  const int lane = t & 63, wave = t >> 6;
  __shared__ int wbase[8];
  __shared__ int wpop[8];
  int v = (t < 500) ? (int)maskb[b * 500 + t] : 0;
  unsigned long long bal = __ballot(v != 0);
  karr[b * 512 + t] = 0xFFFF;
  if (lane == 0) wpop[wave] = __popcll(bal);
  __syncthreads();
  if (t == 0) {
    int s = 0;
    for (int w = 0; w < 8; ++w) { wbase[w] = s; s += wpop[w]; }
    kept[b] = s;
  }
  __syncthreads();
  if (v) {
    int rank = wbase[wave] + __popcll(bal & ((1ull << lane) - 1ull));
    karr[b * 512 + rank] = (u16)t;
  }
}

// ---------------- rope cos/sin table: tab[(s*32+j)*2] = cos, +1 = sin ----------------
__global__ __launch_bounds__(256) void rope_table(float* __restrict__ tab) {
  int idx = blockIdx.x * 256 + threadIdx.x;
  if (idx >= 16000) return;
  int s = idx >> 5, j = idx & 31;
  float ang = (float)s * exp2f(-(float)j * 0.41524100f);  // 10000^(-j/32)
  float sn, cs;
  sincosf(ang, &sn, &cs);
  tab[idx * 2] = cs;
  tab[idx * 2 + 1] = sn;
}

// ---------------- f32 -> bf16 convert (vectorized) ----------------
__global__ __launch_bounds__(256) void cvt_f32_bf16(const float* __restrict__ src,
                                                    u16* __restrict__ dst, int n4) {
  int i = blockIdx.x * 256 + threadIdx.x;
  int stride = gridDim.x * 256;
  for (; i < n4; i += stride) {
    f32x4 f = *(const f32x4*)(src + (size_t)i * 4);
    u16x4 o;
    o[0] = f2bf(f[0]); o[1] = f2bf(f[1]); o[2] = f2bf(f[2]); o[3] = f2bf(f[3]);
    *(u16x4*)(dst + (size_t)i * 4) = o;
  }
}

// ---------------- GEMM: C[m][n] = sum_k A[m][k]*Bw[n][k] + bias[n], 2-phase prefetch ---------
template <bool OUT_BF16>
__global__ __launch_bounds__(256) void gemm_bt(const u16* __restrict__ A,
                                               const u16* __restrict__ Bw,
                                               const float* __restrict__ bias,
                                               void* __restrict__ Cout) {
  const int bid = blockIdx.x;
  const int swz = (bid & 7) * 125 + (bid >> 3);   // bijective: 1000 = 8*125; XCD L2 reuse
  const int m0 = (swz >> 3) * 128;
  const int n0 = (swz & 7) * 128;
  const int tid  = threadIdx.x;
  const int wave = tid >> 6;
  const int wr = wave >> 1, wc = wave & 1;
  const int fr = tid & 15, fo = (tid >> 4) & 3;

  __shared__ __attribute__((aligned(16))) u16 As[2][128 * 32];
  __shared__ __attribute__((aligned(16))) u16 Bs[2][128 * 32];

  f32x4 acc[4][4];
#pragma unroll
  for (int mi = 0; mi < 4; ++mi)
#pragma unroll
    for (int ni = 0; ni < 4; ++ni)
#pragma unroll
      for (int j = 0; j < 4; ++j) acc[mi][ni][j] = 0.f;

  // prologue: stage kt=0 into buf0
#pragma unroll
  for (int i = 0; i < 2; ++i) {
    int slot = i * 256 + tid;
    int r2 = slot >> 2, s2 = slot & 3;
    async16(&As[0][slot * 8], A + (size_t)(m0 + r2) * 1024 + s2 * 8);
    async16(&Bs[0][slot * 8], Bw + (size_t)(n0 + r2) * 1024 + s2 * 8);
  }
  __syncthreads();

  for (int kt = 0; kt < 32; ++kt) {
    const int cur = kt & 1;
    if (kt + 1 < 32) {                      // issue next-tile loads before compute
#pragma unroll
      for (int i = 0; i < 2; ++i) {
        int slot = i * 256 + tid;
        int r2 = slot >> 2, s2 = slot & 3;
        async16(&As[cur ^ 1][slot * 8], A + (size_t)(m0 + r2) * 1024 + (kt + 1) * 32 + s2 * 8);
        async16(&Bs[cur ^ 1][slot * 8], Bw + (size_t)(n0 + r2) * 1024 + (kt + 1) * 32 + s2 * 8);
      }
    }
    const u16* Ac = cur ? &As[1][0] : &As[0][0];
    const u16* Bc = cur ? &Bs[1][0] : &Bs[0][0];
    bf16x8 a[4], b[4];
#pragma unroll
    for (int mi = 0; mi < 4; ++mi)
      a[mi] = *(const bf16x8*)&Ac[(wr * 64 + mi * 16 + fr) * 32 + fo * 8];
#pragma unroll
    for (int ni = 0; ni < 4; ++ni)
      b[ni] = *(const bf16x8*)&Bc[(wc * 64 + ni * 16 + fr) * 32 + fo * 8];
#pragma unroll
    for (int mi = 0; mi < 4; ++mi)
#pragma unroll
      for (int ni = 0; ni < 4; ++ni)
        acc[mi][ni] = __builtin_amdgcn_mfma_f32_16x16x32_bf16(a[mi], b[ni], acc[mi][ni], 0, 0, 0);
    __syncthreads();   // drains next-tile vmcnt + this tile's lgkm
  }

#pragma unroll
  for (int ni = 0; ni < 4; ++ni) {
    int n = n0 + wc * 64 + ni * 16 + fr;
    float bv = bias[n];
#pragma unroll
    for (int mi = 0; mi < 4; ++mi) {
#pragma unroll
      for (int r = 0; r < 4; ++r) {
        int m = m0 + wr * 64 + mi * 16 + fo * 4 + r;   // C/D: col=lane&15, row=(lane>>4)*4+reg
        float v = acc[mi][ni][r] + bv;
        if (OUT_BF16) ((u16*)Cout)[(size_t)m * 1024 + n] = f2bf(v);
        else          ((float*)Cout)[(size_t)m * 1024 + n] = v;
      }
    }
  }
}

// ---------------- rope Q + [B*S][H] -> [B][NH][S][HD]; 2 outputs/thread ----------------
__global__ __launch_bounds__(256) void rope_q(const u16* __restrict__ P,
                                              const float* __restrict__ tab,
                                              u16* __restrict__ R) {
  int idx = blockIdx.x * 256 + threadIdx.x;   // 8,192,000 = 512 bh * 500 s * 32 j
  int j = idx & 31;
  int t = idx >> 5;
  int s = t % 500;
  int bh = t / 500;
  int h = bh & 15, b = bh >> 4;
  size_t src = (size_t)(b * 500 + s) * 1024 + h * 64;
  float x0 = bf2f(P[src + j]);
  float x1 = bf2f(P[src + 32 + j]);
  float xe = bf2f(P[src + 2 * j]);
  float xo = bf2f(P[src + 2 * j + 1]);
  f32x2 cn = *(const f32x2*)(tab + (s * 32 + j) * 2);
  size_t dst = (size_t)t * 64;
  R[dst + j]      = f2bf(x0 * cn[0] - xo * cn[1]);   // d<32
  R[dst + 32 + j] = f2bf(x1 * cn[0] + xe * cn[1]);   // d>=32
}

// ---------------- K: rope + gather kept tokens -> pre-swizzled tiles [bh][tile][64][128B] ------
// image[row][byte B] = K_rope[tok(row)][ (B ^ ((row&7)<<4)) / 2 ]
__global__ __launch_bounds__(256) void gather_k(const u16* __restrict__ Pk,
                                                const float* __restrict__ tab,
                                                const u16* __restrict__ karr,
                                                const int* __restrict__ kept,
                                                u16* __restrict__ Ktg) {
  const int tile = blockIdx.x;
  const int bh = blockIdx.y;
  const int h = bh & 15, b = bh >> 4;
  if (tile * 64 >= kept[b]) return;
  char* out = (char*)(Ktg + ((size_t)bh * 8 + tile) * 4096);
  const int tid = threadIdx.x;
#pragma unroll
  for (int i = 0; i < 8; ++i) {
    int item = i * 256 + tid;            // 2048 = 64 rows * 32 j
    int row = item >> 5, j = item & 31;
    int tok = karr[b * 512 + tile * 64 + row];
    int sw = (row & 7) << 4;
    u16 o0 = 0, o1 = 0;
    if (tok != 0xFFFF) {
      const u16* src = Pk + ((size_t)b * 500 + tok) * 1024 + h * 64;   // FIX: + b*500
      float x0 = bf2f(src[j]);
      float x1 = bf2f(src[32 + j]);
      float xe = bf2f(src[2 * j]);
      float xo = bf2f(src[2 * j + 1]);
      f32x2 cn = *(const f32x2*)(tab + (tok * 32 + j) * 2);
      o0 = f2bf(x0 * cn[0] - xo * cn[1]);
      o1 = f2bf(x1 * cn[0] + xe * cn[1]);
    }
    *(u16*)(out + row * 128 + ((2 * j) ^ sw)) = o0;
    *(u16*)(out + row * 128 + ((64 + 2 * j) ^ sw)) = o1;
  }
}

// ---------------- V: gather + transpose -> pre-swizzled V^T tiles [bh][tile][64 d][128B] ------
// image[d][byte B] = V[tok( (B ^ ((d&7)<<4))/2 )][d]
__global__ __launch_bounds__(256) void gather_v(const u16* __restrict__ Pv,
                                                const u16* __restrict__ karr,
                                                const int* __restrict__ kept,
                                                u16* __restrict__ Vtg) {
  const int tile = blockIdx.x;
  const int bh = blockIdx.y;
  const int h = bh & 15, b = bh >> 4;
  if (tile * 64 >= kept[b]) return;
  const int tid = threadIdx.x;
  __shared__ __attribute__((aligned(16))) u16 Vl[64 * 64];
#pragma unroll
  for (int i = 0; i < 2; ++i) {
    int chunk = i * 256 + tid;           // 512: slot(64) x seg(8)
    int slot = chunk >> 3, seg = chunk & 7;
    int tok = karr[b * 512 + tile * 64 + slot];
    bf16x8 v;
#pragma unroll
    for (int p = 0; p < 8; ++p) v[p] = 0;
    if (tok != 0xFFFF)
      v = *(const bf16x8*)(Pv + ((size_t)b * 500 + tok) * 1024 + h * 64 + seg * 8);  // FIX: + b*500
    *(bf16x8*)&Vl[slot * 64 + seg * 8] = v;
  }
  __syncthreads();
  u16* out = Vtg + ((size_t)bh * 8 + tile) * 4096;
#pragma unroll
  for (int i = 0; i < 2; ++i) {
    int chunk = i * 256 + tid;           // d(64) x c16(8)
    int d = chunk >> 3, c16 = chunk & 7;
    int k0 = ((c16 * 16) ^ ((d & 7) << 4)) >> 1;
    bf16x8 v;
#pragma unroll
    for (int p = 0; p < 8; ++p) v[p] = (short)Vl[(k0 + p) * 64 + d];
    *(bf16x8*)(out + chunk * 8) = v;
  }
}

// ---------------- flash attention: compressed k, swapped QK^T, in-reg softmax ----------------
// grid 2048: bid -> xcd-major so the 4 q-blocks of a head share an XCD (K/V L2 reuse).
// 8 waves x 16 q-rows = 128 q per block; k tiles of 64 kept positions.
__global__ __launch_bounds__(512) void attn_kernel(const u16* __restrict__ Qr,
                                                   const u16* __restrict__ Ktg,
                                                   const u16* __restrict__ Vtg,
                                                   const float* __restrict__ rel_emb,
                                                   const u16* __restrict__ karr,
                                                   const int* __restrict__ kept,
                                                   u16* __restrict__ AO) {
  const int bid = blockIdx.x;
  const int bh = ((bid >> 5) << 3) | (bid & 7);
  const int qb = (bid >> 3) & 3;
  const int h = bh & 15, b = bh >> 4;
  const int q0 = qb * 128;
  const int tid = threadIdx.x;
  const int wave = tid >> 6;
  const int fr = tid & 15, fo = (tid >> 4) & 3;

  __shared__ __attribute__((aligned(16))) u16 Ks[2][4096];   // 8KB pre-swizzled K tile x2
  __shared__ __attribute__((aligned(16))) u16 Vs[2][4096];   // 8KB pre-swizzled V^T tile x2
  __shared__ __attribute__((aligned(16))) u16 Pl[8][1024];   // per-wave P / epilogue bounce
  __shared__ float rel2[640];                                // rel window * log2e
  __shared__ u16 okk[512];                                   // orig token per slot (0xFFFF pad)

  const int nk = kept[b];
  const int nt = (nk + 63) >> 6;
  const float LOG2E = 1.44269504f;
  for (int i = tid; i < 640; i += 512) {
    int g = min(max(q0 - 12 + i, 0), 998);
    rel2[i] = rel_emb[g * 16 + h] * LOG2E;
  }
  okk[tid] = karr[b * 512 + tid];

  const int qloc = wave * 16 + fr;       // this lane's q (output column)
  const int qg = q0 + qloc;
  const bool qok = (qg < 500);
  const u16* Qb = Qr + ((size_t)bh * 500 + min(qg, 499)) * 64;
  bf16x8 qf0 = *(const bf16x8*)(Qb + fo * 8);        // B-frag: lane&15=q, fo*8=d-chunk
  bf16x8 qf1 = *(const bf16x8*)(Qb + 32 + fo * 8);

  f32x4 o[4];                            // o[nf][r]: d = nf*16+fo*4+r, q = fr (lane-local)
#pragma unroll
  for (int nf = 0; nf < 4; ++nf)
#pragma unroll
    for (int j = 0; j < 4; ++j) o[nf][j] = 0.f;
  float mrun = -1e30f, lrun = 0.f;       // per-lane scalars (q = fr)

  const u16* Kb = Ktg + (size_t)bh * 32768;
  const u16* Vb = Vtg + (size_t)bh * 32768;
  const int sw = (fr & 7) << 4;
  const float SC = 0.18033688f;          // 0.125 * log2(e)

  if (nt > 0) {
    async16(&Ks[0][tid * 8], Kb + tid * 8);
    async16(&Vs[0][tid * 8], Vb + tid * 8);
  }
  __syncthreads();

  for (int t = 0; t < nt; ++t) {
    const int cur = t & 1;
    if (t + 1 < nt) {                    // prefetch next tile into other buffer
      async16(&Ks[cur ^ 1][tid * 8], Kb + (t + 1) * 4096 + tid * 8);
      async16(&Vs[cur ^ 1][tid * 8], Vb + (t + 1) * 4096 + tid * 8);
    }
    const char* Kt = (const char*)(cur ? &Ks[1][0] : &Ks[0][0]);
    const char* Vt = (const char*)(cur ? &Vs[1][0] : &Vs[0][0]);

    // swapped QK^T: C[k][q] -> lane holds k = nf*16+fo*4+r for its q=fr
    f32x4 sacc[4];
    __builtin_amdgcn_s_setprio(1);
#pragma unroll
    for (int nf = 0; nf < 4; ++nf) {
#pragma unroll
      for (int jj = 0; jj < 4; ++jj) sacc[nf][jj] = 0.f;
      int rb = (nf * 16 + fr) * 128;
      bf16x8 kb0 = *(const bf16x8*)(Kt + rb + ((fo * 16) ^ sw));
      bf16x8 kb1 = *(const bf16x8*)(Kt + rb + ((64 + fo * 16) ^ sw));
      sacc[nf] = __builtin_amdgcn_mfma_f32_16x16x32_bf16(kb0, qf0, sacc[nf], 0, 0, 0);
      sacc[nf] = __builtin_amdgcn_mfma_f32_16x16x32_bf16(kb1, qf1, sacc[nf], 0, 0, 0);
    }
    __builtin_amdgcn_s_setprio(0);

    // scores (log2 domain) + in-register row max
    float p2[4][4];
    float pmax = -1e30f;
#pragma unroll
    for (int nf = 0; nf < 4; ++nf) {
#pragma unroll
      for (int r = 0; r < 4; ++r) {
        int slot = t * 64 + nf * 16 + fo * 4 + r;
        int ok = okk[slot];
        float rv = rel2[min(max(qloc - ok + 511, 0), 639)];
        bool valid = (ok != 0xFFFF) && qok;
        float s2 = valid ? fmaf(sacc[nf][r], SC, rv) : -1e30f;
        p2[nf][r] = s2;
        pmax = fmaxf(pmax, s2);
      }
    }
    pmax = fmaxf(pmax, __shfl_xor(pmax, 16, 64));
    pmax = fmaxf(pmax, __shfl_xor(pmax, 32, 64));

    if (!__all(pmax <= mrun + 8.0f)) {   // defer-max (T13): skip rescale on small growth
      float mnew = fmaxf(mrun, pmax);
      float scl = EXP2(mrun - mnew);
      lrun *= scl;
#pragma unroll
      for (int nf = 0; nf < 4; ++nf)
#pragma unroll
        for (int r = 0; r < 4; ++r) o[nf][r] *= scl;
      mrun = mnew;
    }

    float lsum = 0.f;
#pragma unroll
    for (int nf = 0; nf < 4; ++nf) {
      float e0 = EXP2(p2[nf][0] - mrun);
      float e1 = EXP2(p2[nf][1] - mrun);
      float e2 = EXP2(p2[nf][2] - mrun);
      float e3 = EXP2(p2[nf][3] - mrun);
      lsum += (e0 + e1) + (e2 + e3);
      uint2 w; w.x = packbf(e0, e1); w.y = packbf(e2, e3);
      *(uint2*)((char*)&Pl[wave][0] + fr * 128 + ((nf * 32 + fo * 8) ^ sw)) = w;
    }
    lsum += __shfl_xor(lsum, 16, 64);
    lsum += __shfl_xor(lsum, 32, 64);
    lrun += lsum;

    // PV flipped: mfma(V^T, P) -> C[d][q], q stays lane-local
    bf16x8 pa0 = *(const bf16x8*)((char*)&Pl[wave][0] + fr * 128 + ((fo * 16) ^ sw));
    bf16x8 pa1 = *(const bf16x8*)((char*)&Pl[wave][0] + fr * 128 + ((64 + fo * 16) ^ sw));
    __builtin_amdgcn_s_setprio(1);
#pragma unroll
    for (int nf = 0; nf < 4; ++nf) {
      int rb = (nf * 16 + fr) * 128;
      bf16x8 vb0 = *(const bf16x8*)(Vt + rb + ((fo * 16) ^ sw));
      bf16x8 vb1 = *(const bf16x8*)(Vt + rb + ((64 + fo * 16) ^ sw));
      o[nf] = __builtin_amdgcn_mfma_f32_16x16x32_bf16(vb0, pa0, o[nf], 0, 0, 0);
      o[nf] = __builtin_amdgcn_mfma_f32_16x16x32_bf16(vb1, pa1, o[nf], 0, 0, 0);
    }
    __builtin_amdgcn_s_setprio(0);
    __syncthreads();
  }

  // epilogue: per-lane normalize+clip, LDS bounce for coalesced stores
  float inv = (lrun > 0.f) ? 1.f / lrun : 0.f;
#pragma unroll
  for (int nf = 0; nf < 4; ++nf) {
    float v0 = fminf(fmaxf(o[nf][0] * inv, -30.f), 30.f);
    float v1 = fminf(fmaxf(o[nf][1] * inv, -30.f), 30.f);
    float v2 = fminf(fmaxf(o[nf][2] * inv, -30.f), 30.f);
    float v3 = fminf(fmaxf(o[nf][3] * inv, -30.f), 30.f);
    uint2 w; w.x = packbf(v0, v1); w.y = packbf(v2, v3);
    *(uint2*)((char*)&Pl[wave][0] + fr * 128 + ((nf * 32 + fo * 8) ^ sw)) = w;
  }
  {
    int lane = tid & 63;
    int ro = lane >> 2, c = lane & 3;
    int swr = (ro & 7) << 4;
    const char* Pw = (const char*)&Pl[wave][0];
    bf16x8 v0 = *(const bf16x8*)(Pw + ro * 128 + ((c * 32) ^ swr));
    bf16x8 v1 = *(const bf16x8*)(Pw + ro * 128 + ((c * 32 + 16) ^ swr));
    int token = q0 + wave * 16 + ro;
    if (token < 500) {
      u16* dst = AO + (size_t)(b * 500 + token) * 1024 + h * 64 + c * 16;
      *(bf16x8*)dst = v0;
      *(bf16x8*)(dst + 8) = v1;
    }
  }
}

// ---------------- launch ----------------
extern "C" void kernel_launch(void* const* d_in, const int* in_sizes, int n_in,
                              void* d_out, int out_size, void* d_ws, size_t ws_size,
                              hipStream_t stream) {
  const float* query = (const float*)d_in[0];
  const float* key_  = (const float*)d_in[1];
  const float* value = (const float*)d_in[2];
  const void*  mask  = d_in[3];
  const float* Wq = (const float*)d_in[4];
  const float* bq = (const float*)d_in[5];
  const float* Wk = (const float*)d_in[6];
  const float* bk = (const float*)d_in[7];
  const float* Wv = (const float*)d_in[8];
  const float* bv = (const float*)d_in[9];
  const float* Wo = (const float*)d_in[10];
  const float* bo = (const float*)d_in[11];
  const float* rel = (const float*)d_in[12];

  // ws map: Wb 8.39MB | 4 slots x 32MiB | misc ~0.26MB  (total ~136.3 MiB)
  // slot liveness: A: Xq->Pk->Vtg | B: Xk->Qro | C: Xv->Pq->Ktg | D: Pv->AO
  char* ws = (char*)d_ws;
  const size_t SLOT = 33554432;
  u16* Wb = (u16*)ws;
  char* Aq = ws + 8388608;
  char* Bq = Aq + SLOT;
  char* Cq = Bq + SLOT;
  char* Dq = Cq + SLOT;
  char* MISC = Dq + SLOT;
  u8*  maskb = (u8*)MISC;
  u16* karr  = (u16*)(MISC + 65536);
  int* kept  = (int*)(MISC + 131072);
  float* tab = (float*)(MISC + 131584);

  mask_prep<<<1, 256, 0, stream>>>(mask, maskb);
  build_gather<<<32, 512, 0, stream>>>(maskb, karr, kept);
  rope_table<<<63, 256, 0, stream>>>(tab);

  cvt_f32_bf16<<<512, 256, 0, stream>>>(Wq, Wb + 0 * 1048576, 262144);
  cvt_f32_bf16<<<512, 256, 0, stream>>>(Wk, Wb + 1 * 1048576, 262144);
  cvt_f32_bf16<<<512, 256, 0, stream>>>(Wv, Wb + 2 * 1048576, 262144);
  cvt_f32_bf16<<<512, 256, 0, stream>>>(Wo, Wb + 3 * 1048576, 262144);
  cvt_f32_bf16<<<2048, 256, 0, stream>>>(query, (u16*)Aq, 4096000);
  cvt_f32_bf16<<<2048, 256, 0, stream>>>(key_,  (u16*)Bq, 4096000);
  cvt_f32_bf16<<<2048, 256, 0, stream>>>(value, (u16*)Cq, 4096000);

  gemm_bt<true><<<1000, 256, 0, stream>>>((u16*)Cq, Wb + 2 * 1048576, bv, Dq);  // Pv=D
  gemm_bt<true><<<1000, 256, 0, stream>>>((u16*)Aq, Wb + 0 * 1048576, bq, Cq);  // Pq=C
  gemm_bt<true><<<1000, 256, 0, stream>>>((u16*)Bq, Wb + 1 * 1048576, bk, Aq);  // Pk=A

  rope_q<<<32000, 256, 0, stream>>>((u16*)Cq, tab, (u16*)Bq);                   // Qro=B
  gather_k<<<dim3(8, 512), 256, 0, stream>>>((u16*)Aq, tab, karr, kept, (u16*)Cq);  // Ktg=C
  gather_v<<<dim3(8, 512), 256, 0, stream>>>((u16*)Dq, karr, kept, (u16*)Aq);       // Vtg=A

  attn_kernel<<<2048, 512, 0, stream>>>((u16*)Bq, (u16*)Cq, (u16*)Aq, rel,
                                        karr, kept, (u16*)Dq);                  // AO=D

  gemm_bt<false><<<1000, 256, 0, stream>>>((u16*)Dq, Wb + 3 * 1048576, bo, (float*)d_out);
}